// Round 5
// baseline (135.368 us; speedup 1.0000x reference)
//
#include <hip/hip_runtime.h>

#pragma clang fp contract(off)

#define N_PTS   16384
#define N_SEEDS 20
#define KP1     11      // K+1, K=10
#define NBIN    512     // bits(d2) >> 22 : exponent + 1 mantissa bit
#define NREP    32      // bank replicas: hist[bin*32 + (t&31)] -> bank == t&31
#define CAP     1024    // candidate buffer capacity

typedef unsigned long long u64;
typedef unsigned int       u32;

// ---------------------------------------------------------------------------
// Fused FPS + kNN-select. One block per batch, 1024 threads, 16 pts/thread
// in NAMED registers. Each FPS iteration computes d(p, seed_it) for every
// point — exactly the distances kNN needs for seed it — so the 11 smallest
// are radix-selected in the same iteration from registers.
//   - seed selection: exact-form arithmetic, first-index tie-break at every
//     level (lane order == index order; wave order == index order) -> seeds
//     bitwise-identical to jnp reference (proven absmax 0.0 rounds 1-4).
//   - select: float-bit radix histogram, bank-replicated to kill same-address
//     LDS-atomic serialization; ~25 candidates; 1-wave rank-select.
// ---------------------------------------------------------------------------
__global__ __launch_bounds__(1024, 4) void fps_knn_kernel(const float* __restrict__ pcs,
                                                          float* __restrict__ topd) {
    const int b = blockIdx.x;
    const float* __restrict__ P  = pcs + (size_t)b * N_PTS * 3;
    const float4* __restrict__ P4 = (const float4*)P;
    const int t    = threadIdx.x;
    const int lane = t & 63;
    const int wid  = t >> 6;
    const int rep  = t & 31;

#define FDECL(i) float px##i, py##i, pz##i, dd##i = 1e10f;
    FDECL(0)  FDECL(1)  FDECL(2)  FDECL(3)
    FDECL(4)  FDECL(5)  FDECL(6)  FDECL(7)
    FDECL(8)  FDECL(9)  FDECL(10) FDECL(11)
    FDECL(12) FDECL(13) FDECL(14) FDECL(15)

    {   // 16 pts * 3 floats = 48 floats = 12 float4 per thread, contiguous
        const int f4 = t * 12;
        const float4 q0 = P4[f4+0],  q1 = P4[f4+1],  q2  = P4[f4+2];
        const float4 q3 = P4[f4+3],  q4 = P4[f4+4],  q5  = P4[f4+5];
        const float4 q6 = P4[f4+6],  q7 = P4[f4+7],  q8  = P4[f4+8];
        const float4 q9 = P4[f4+9],  q10 = P4[f4+10], q11 = P4[f4+11];
        px0 =q0.x;  py0 =q0.y;  pz0 =q0.z;
        px1 =q0.w;  py1 =q1.x;  pz1 =q1.y;
        px2 =q1.z;  py2 =q1.w;  pz2 =q2.x;
        px3 =q2.y;  py3 =q2.z;  pz3 =q2.w;
        px4 =q3.x;  py4 =q3.y;  pz4 =q3.z;
        px5 =q3.w;  py5 =q4.x;  pz5 =q4.y;
        px6 =q4.z;  py6 =q4.w;  pz6 =q5.x;
        px7 =q5.y;  py7 =q5.z;  pz7 =q5.w;
        px8 =q6.x;  py8 =q6.y;  pz8 =q6.z;
        px9 =q6.w;  py9 =q7.x;  pz9 =q7.y;
        px10=q7.z;  py10=q7.w;  pz10=q8.x;
        px11=q8.y;  py11=q8.z;  pz11=q8.w;
        px12=q9.x;  py12=q9.y;  pz12=q9.z;
        px13=q9.w;  py13=q10.x; pz13=q10.y;
        px14=q10.z; py14=q10.w; pz14=q11.x;
        px15=q11.y; py15=q11.z; pz15=q11.w;
    }

    __shared__ u32   hist[NBIN * NREP];   // 64 KB
    __shared__ u32   part[NBIN];
    __shared__ float s_val[2][16];
    __shared__ int   s_idx[2][16];
    __shared__ float cand[CAP];
    __shared__ u32   cnt;
    __shared__ u32   s_thr;

    // zero histogram + counter once; per-iteration re-zero happens in-loop
#pragma unroll
    for (int i = 0; i < (NBIN * NREP) / 1024; ++i) hist[t + i * 1024] = 0u;
    if (t == 0) cnt = 0u;

    float cx = P[0], cy = P[1], cz = P[2];   // centroid of seed 0 (index 0)
    __syncthreads();

    for (int it = 0; it < N_SEEDS; ++it) {
        // ---- FSTEP: distance, running-min, argmax-track, histogram --------
        float bestv = -1.0f;
        int   besti = 0;
        float d0,d1,d2,d3,d4,d5,d6,d7,d8,d9,d10,d11,d12,d13,d14,d15;
#define FSTEP(i) { const float dx = px##i - cx, dy = py##i - cy, dz = pz##i - cz; \
        d##i = (dx*dx + dy*dy) + dz*dz; \
        const float nd = fminf(dd##i, d##i); dd##i = nd; \
        if (nd > bestv) { bestv = nd; besti = t*16 + (i); } \
        atomicAdd(&hist[(__float_as_uint(d##i) >> 22) * NREP + rep], 1u); }
        FSTEP(0)  FSTEP(1)  FSTEP(2)  FSTEP(3)
        FSTEP(4)  FSTEP(5)  FSTEP(6)  FSTEP(7)
        FSTEP(8)  FSTEP(9)  FSTEP(10) FSTEP(11)
        FSTEP(12) FSTEP(13) FSTEP(14) FSTEP(15)

        // ---- level-1: wave argmax (float max + ballot, first-index tie) ---
        float wmax = bestv;
        for (int off = 32; off; off >>= 1)
            wmax = fmaxf(wmax, __shfl_xor(wmax, off));
        const u64 msk = __ballot(bestv == wmax);
        const int low = __ffsll((unsigned long long)msk) - 1;
        const int wi  = __shfl(besti, low);
        const int par = it & 1;
        if (lane == 0) { s_val[par][wid] = wmax; s_idx[par][wid] = wi; }
        __syncthreads();                      // B1: hist complete, s_val ready

        // ---- level-2: block argmax over 16 wave maxima (all threads) ------
        const float v16 = s_val[par][lane & 15];
        float g = v16;
        for (int off = 1; off < 16; off <<= 1)
            g = fmaxf(g, __shfl_xor(g, off));
        const u64 m2 = __ballot(v16 == g) & 0xFFFFull;
        const int ws = __ffsll((unsigned long long)m2) - 1;
        const int widx = s_idx[par][ws];
        // issue next-centroid load now; latency hides under the scan phase
        const int fi = __builtin_amdgcn_readfirstlane(widx);
        const float ncx = P[fi*3+0], ncy = P[fi*3+1], ncz = P[fi*3+2];

        // ---- scan A: fold 32 replicas per bin (rotated, conflict-free) ----
        if (t < NBIN) {
            u32 s = 0;
#pragma unroll
            for (int r = 0; r < NREP; ++r)
                s += hist[t * NREP + ((r + t) & (NREP - 1))];
            part[t] = s;
        }
        if (t == 1023) cnt = 0u;              // reset for this iter's collect
        __syncthreads();                      // B2: part[] ready

        // ---- threshold (wave 0) || histogram re-zero (waves 1..15) --------
        if (wid == 0) {
            u32 s8 = 0;
#pragma unroll
            for (int i = 0; i < 8; ++i)
                s8 += part[lane * 8 + ((i + lane) & 7)];
            u32 cum = s8;
            for (int off = 1; off < 64; off <<= 1) {
                const u32 o = __shfl_up(cum, off);
                if (lane >= off) cum += o;
            }
            const u64 mm = __ballot(cum >= (u32)KP1);
            const int L  = __ffsll((unsigned long long)mm) - 1;
            const u32 below = __shfl(cum - s8, L);      // count before chunk L
            const u32 bc = (lane < 8) ? part[L * 8 + lane] : 0u;
            u32 ic = bc;
            for (int off = 1; off < 8; off <<= 1) {
                const u32 o = __shfl_up(ic, off);
                if (lane >= off) ic += o;
            }
            const u64 mm2 = __ballot(lane < 8 && (below + ic) >= (u32)KP1);
            const int l2  = __ffsll((unsigned long long)mm2) - 1;
            if (lane == 0) s_thr = (u32)(L * 8 + l2 + 1) << 22;
        } else {
            for (int i = t - 64; i < NBIN * NREP; i += 960) hist[i] = 0u;
        }
        __syncthreads();                      // B3: thr ready, hist zeroed

        // ---- collect candidates from registers ----------------------------
        const float thrf = __uint_as_float(s_thr);
#define COLL(i) if (d##i < thrf) { const u32 sl = atomicAdd(&cnt, 1u); \
                                   if (sl < (u32)CAP) cand[sl] = d##i; }
        COLL(0)  COLL(1)  COLL(2)  COLL(3)
        COLL(4)  COLL(5)  COLL(6)  COLL(7)
        COLL(8)  COLL(9)  COLL(10) COLL(11)
        COLL(12) COLL(13) COLL(14) COLL(15)
        __syncthreads();                      // B4: candidates ready

        // ---- rank-select 11 smallest (wave 0); others run ahead to FSTEP --
        if (wid == 0) {
            const u32 n = min(cnt, (u32)CAP);
            for (u32 base = 0; base < n; base += 64) {
                const u32 idx = base + (u32)lane;
                const float vv = (idx < n) ? cand[idx] : 3.0e38f;
                u32 r = 0;
                for (u32 j = 0; j < n; ++j) {
                    const float w = cand[j];
                    r += (w < vv || (w == vv && j < idx)) ? 1u : 0u;
                }
                if (idx < n && r < (u32)KP1)
                    topd[(b * N_SEEDS + it) * KP1 + r] = sqrtf(vv);
            }
        }
        cx = ncx; cy = ncy; cz = ncz;
    }
}

// ---------------------------------------------------------------------------
// stats (UNCHANGED): overall_mean over [:,:,1:], per-seed means, unbiased
// variance; fp64 accumulation.
// ---------------------------------------------------------------------------
__global__ __launch_bounds__(256) void stats_kernel(const float* __restrict__ topd,
                                                    float* __restrict__ out, int B) {
    const int pairs = B * N_SEEDS;
    const int total = pairs * KP1;
    const int t = threadIdx.x;
    __shared__ double red[256];
    __shared__ double om_s;

    double s1 = 0.0;
    for (int i = t; i < total; i += 256)
        if (i % KP1 != 0) s1 += (double)topd[i];
    red[t] = s1;
    __syncthreads();
    for (int off = 128; off > 0; off >>= 1) {
        if (t < off) red[t] += red[t + off];
        __syncthreads();
    }
    if (t == 0) om_s = red[0] / (double)(pairs * (KP1 - 1));
    __syncthreads();
    const double om = om_s;

    double sm = 0.0, sm2 = 0.0;
    for (int pr = t; pr < pairs; pr += 256) {
        double acc = 0.0;
        for (int j = 0; j < KP1; ++j) acc += (double)topd[pr * KP1 + j];
        const double m = acc / (om * (double)KP1);
        sm += m;
        sm2 += m * m;
    }
    red[t] = sm;
    __syncthreads();
    for (int off = 128; off > 0; off >>= 1) {
        if (t < off) red[t] += red[t + off];
        __syncthreads();
    }
    double Sm = 0.0;
    if (t == 0) Sm = red[0];
    __syncthreads();
    red[t] = sm2;
    __syncthreads();
    for (int off = 128; off > 0; off >>= 1) {
        if (t < off) red[t] += red[t + off];
        __syncthreads();
    }
    if (t == 0) {
        const double var = (red[0] - Sm * Sm / (double)pairs) / (double)(pairs - 1);
        out[0] = (float)var;
    }
}

// ---------------------------------------------------------------------------
extern "C" void kernel_launch(void* const* d_in, const int* in_sizes, int n_in,
                              void* d_out, int out_size, void* d_ws, size_t ws_size,
                              hipStream_t stream) {
    const float* pcs = (const float*)d_in[0];
    const int B = in_sizes[0] / (N_PTS * 3);

    float* topd = (float*)d_ws;
    float* out  = (float*)d_out;

    fps_knn_kernel<<<B, 1024, 0, stream>>>(pcs, topd);
    stats_kernel<<<1, 256, 0, stream>>>(topd, out, B);
}

// Round 6
// 110.002 us; speedup vs baseline: 1.2306x; 1.2306x over previous
//
#include <hip/hip_runtime.h>

#pragma clang fp contract(off)

#define N_PTS   16384
#define N_SEEDS 20
#define KP1     11      // K+1, K=10
#define NBIN    512     // bits(d2) >> 22 : exponent + 1 mantissa bit
#define NREP    32      // hist[bin*32 + (t&31)] -> bank == t&31 (conflict-free)
#define CAP     1024
#define NKNN    3       // knn-role blocks per batch
#define SEG     7       // ceil(N_SEEDS / NKNN)

typedef unsigned long long u64;
typedef unsigned int       u32;

__device__ __forceinline__ u64 shfl_xor_u64(u64 v, int off) {
    int lo = __shfl_xor((int)(u32)(v & 0xffffffffull), off);
    int hi = __shfl_xor((int)(u32)(v >> 32), off);
    return ((u64)(u32)hi << 32) | (u32)lo;
}

// load 16 consecutive points (t*16 .. t*16+15) into named regs px0..pz15
#define FDECL(i) float px##i, py##i, pz##i, dd##i = 1e10f;
#define LOADPTS(P4)                                                         \
    {   const int f4 = t * 12;                                              \
        const float4 q0 = P4[f4+0],  q1 = P4[f4+1],  q2  = P4[f4+2];        \
        const float4 q3 = P4[f4+3],  q4 = P4[f4+4],  q5  = P4[f4+5];        \
        const float4 q6 = P4[f4+6],  q7 = P4[f4+7],  q8  = P4[f4+8];        \
        const float4 q9 = P4[f4+9],  q10 = P4[f4+10], q11 = P4[f4+11];      \
        px0 =q0.x;  py0 =q0.y;  pz0 =q0.z;                                  \
        px1 =q0.w;  py1 =q1.x;  pz1 =q1.y;                                  \
        px2 =q1.z;  py2 =q1.w;  pz2 =q2.x;                                  \
        px3 =q2.y;  py3 =q2.z;  pz3 =q2.w;                                  \
        px4 =q3.x;  py4 =q3.y;  pz4 =q3.z;                                  \
        px5 =q3.w;  py5 =q4.x;  pz5 =q4.y;                                  \
        px6 =q4.z;  py6 =q4.w;  pz6 =q5.x;                                  \
        px7 =q5.y;  py7 =q5.z;  pz7 =q5.w;                                  \
        px8 =q6.x;  py8 =q6.y;  pz8 =q6.z;                                  \
        px9 =q6.w;  py9 =q7.x;  pz9 =q7.y;                                  \
        px10=q7.z;  py10=q7.w;  pz10=q8.x;                                  \
        px11=q8.y;  py11=q8.z;  pz11=q8.w;                                  \
        px12=q9.x;  py12=q9.y;  pz12=q9.z;                                  \
        px13=q9.w;  py13=q10.x; pz13=q10.y;                                 \
        px14=q10.z; py14=q10.w; pz14=q11.x;                                 \
        px15=q11.y; py15=q11.z; pz15=q11.w; }

// ---------------------------------------------------------------------------
// One kernel, two block roles, concurrent on one stream:
//   bid <  B : FPS for batch bid (round-4 proven logic), publishes seeds[]
//              with agent-scope release stores.
//   bid >= B : kNN-select role. j = (bid-B)/B in [0,NKNN), batch b=(bid-B)%B,
//              handles seeds [j*SEG, min((j+1)*SEG, 20)). Spins (acquire) on
//              each seed, then float-bit radix-select (round-5 proven).
// 256 blocks x 1024 thr: worst-case 2 blocks/CU on 128 CUs -> always fully
// co-resident -> spin-wait cannot deadlock. bid ≡ b (mod 8) keeps each
// batch's 4 blocks on one XCD (L2-local points).
// ---------------------------------------------------------------------------
__global__ __launch_bounds__(1024) void fused_kernel(const float* __restrict__ pcs,
                                                     int* __restrict__ seeds,
                                                     float* __restrict__ topd,
                                                     int B) {
    __shared__ u32   hist[NBIN * NREP];   // 64 KB (knn role)
    __shared__ u32   part[NBIN];
    __shared__ float cand[CAP];
    __shared__ u32   cnt;
    __shared__ u32   s_thr;
    __shared__ int   s_sid;
    __shared__ u64   s_key[2][16];        // fps role
    __shared__ float s_cx[2][16], s_cy[2][16], s_cz[2][16];

    const int bid  = blockIdx.x;
    const int t    = threadIdx.x;
    const int lane = t & 63;
    const int wid  = t >> 6;

    if (bid < B) {
        // ================= FPS role (frozen round-4 logic) =================
        const float* __restrict__ P  = pcs + (size_t)bid * N_PTS * 3;
        const float4* __restrict__ P4 = (const float4*)P;

        FDECL(0)  FDECL(1)  FDECL(2)  FDECL(3)
        FDECL(4)  FDECL(5)  FDECL(6)  FDECL(7)
        FDECL(8)  FDECL(9)  FDECL(10) FDECL(11)
        FDECL(12) FDECL(13) FDECL(14) FDECL(15)
        LOADPTS(P4)

        float cx = P[0], cy = P[1], cz = P[2];   // centroid of seed 0
        int farthest = 0;

        for (int it = 0; it < N_SEEDS; ++it) {
            if (t == 0)
                __hip_atomic_store(&seeds[bid * N_SEEDS + it], farthest,
                                   __ATOMIC_RELEASE, __HIP_MEMORY_SCOPE_AGENT);

            float bestv = -1.0f, bx = 0.f, by = 0.f, bz = 0.f;
            int   besti = 0;
#define FSTEP(i) { const float dx = px##i - cx, dy = py##i - cy, dz = pz##i - cz; \
        const float d  = (dx*dx + dy*dy) + dz*dz; \
        const float nd = fminf(dd##i, d); dd##i = nd; \
        if (nd > bestv) { bestv = nd; besti = t*16 + (i); \
                          bx = px##i; by = py##i; bz = pz##i; } }
            FSTEP(0)  FSTEP(1)  FSTEP(2)  FSTEP(3)
            FSTEP(4)  FSTEP(5)  FSTEP(6)  FSTEP(7)
            FSTEP(8)  FSTEP(9)  FSTEP(10) FSTEP(11)
            FSTEP(12) FSTEP(13) FSTEP(14) FSTEP(15)

            // wave max + lowest-lane-holding-it (= lowest index)
            float wmax = bestv;
            for (int off = 32; off; off >>= 1)
                wmax = fmaxf(wmax, __shfl_xor(wmax, off));
            const u64 msk = __ballot(bestv == wmax);
            const int low = __ffsll((unsigned long long)msk) - 1;
            const int wi  = __shfl(besti, low);
            const float wx = __shfl(bx, low);
            const float wy = __shfl(by, low);
            const float wz = __shfl(bz, low);

            const int par = it & 1;
            if (lane == 0) {
                s_key[par][wid] = ((u64)__float_as_uint(wmax) << 32) | (u32)(~(u32)wi);
                s_cx[par][wid] = wx; s_cy[par][wid] = wy; s_cz[par][wid] = wz;
            }
            __syncthreads();

            u64 k = s_key[par][lane & 15];
            for (int off = 8; off; off >>= 1) {
                const u64 o = shfl_xor_u64(k, off);
                if (o > k) k = o;
            }
            const int widx = (int)(~(u32)k);
            farthest = widx;
            const int ww = widx >> 10;
            cx = s_cx[par][ww]; cy = s_cy[par][ww]; cz = s_cz[par][ww];
        }
    } else {
        // ================= kNN-select role =================
        const int kk = bid - B;
        const int b  = kk % B;          // bid ≡ b (mod 8) when B%8==0
        const int j  = kk / B;
        const int sBeg = j * SEG;
        const int sEnd = min(sBeg + SEG, N_SEEDS);

        const float* __restrict__ P  = pcs + (size_t)b * N_PTS * 3;
        const float4* __restrict__ P4 = (const float4*)P;
        const int rep = t & 31;

        FDECL(0)  FDECL(1)  FDECL(2)  FDECL(3)
        FDECL(4)  FDECL(5)  FDECL(6)  FDECL(7)
        FDECL(8)  FDECL(9)  FDECL(10) FDECL(11)
        FDECL(12) FDECL(13) FDECL(14) FDECL(15)
        LOADPTS(P4)        // dd regs unused here -> dead-code-eliminated

#pragma unroll
        for (int i = 0; i < (NBIN * NREP) / 1024; ++i) hist[t + i * 1024] = 0u;
        if (t == 0) cnt = 0u;

        for (int s = sBeg; s < sEnd; ++s) {
            if (t == 0) {
                int sv;
                while ((sv = __hip_atomic_load(&seeds[b * N_SEEDS + s],
                               __ATOMIC_ACQUIRE, __HIP_MEMORY_SCOPE_AGENT)) < 0)
                    __builtin_amdgcn_s_sleep(2);
                s_sid = sv;
            }
            __syncthreads();                  // B0: sid ready, hist zero, cnt zero
            const int sid = s_sid;
            const float cx = P[sid*3], cy = P[sid*3+1], cz = P[sid*3+2];

            // ---- histogram pass (d transient, no live d regs) -------------
#define HSTEP(i) { const float dx = px##i - cx, dy = py##i - cy, dz = pz##i - cz; \
        const float d = fmaf(dz, dz, fmaf(dy, dy, dx * dx)); \
        atomicAdd(&hist[(__float_as_uint(d) >> 22) * NREP + rep], 1u); }
            HSTEP(0)  HSTEP(1)  HSTEP(2)  HSTEP(3)
            HSTEP(4)  HSTEP(5)  HSTEP(6)  HSTEP(7)
            HSTEP(8)  HSTEP(9)  HSTEP(10) HSTEP(11)
            HSTEP(12) HSTEP(13) HSTEP(14) HSTEP(15)
            __syncthreads();                  // B1: hist complete

            // ---- fold 32 replicas per bin (rotated, conflict-free) --------
            if (t < NBIN) {
                u32 ssum = 0;
#pragma unroll
                for (int r = 0; r < NREP; ++r)
                    ssum += hist[t * NREP + ((r + t) & (NREP - 1))];
                part[t] = ssum;
            }
            __syncthreads();                  // B2: part[] ready

            // ---- threshold (wave 0) || histogram re-zero (waves 1..15) ----
            if (wid == 0) {
                u32 s8 = 0;
#pragma unroll
                for (int i = 0; i < 8; ++i)
                    s8 += part[lane * 8 + ((i + lane) & 7)];
                u32 cum = s8;
                for (int off = 1; off < 64; off <<= 1) {
                    const u32 o = __shfl_up(cum, off);
                    if (lane >= off) cum += o;
                }
                const u64 mm = __ballot(cum >= (u32)KP1);
                const int L  = __ffsll((unsigned long long)mm) - 1;
                const u32 below = __shfl(cum - s8, L);
                const u32 bc = (lane < 8) ? part[L * 8 + lane] : 0u;
                u32 ic = bc;
                for (int off = 1; off < 8; off <<= 1) {
                    const u32 o = __shfl_up(ic, off);
                    if (lane >= off) ic += o;
                }
                const u64 mm2 = __ballot(lane < 8 && (below + ic) >= (u32)KP1);
                const int l2  = __ffsll((unsigned long long)mm2) - 1;
                if (lane == 0) s_thr = (u32)(L * 8 + l2 + 1) << 22;
            } else {
                for (int i = t - 64; i < NBIN * NREP; i += 960) hist[i] = 0u;
            }
            __syncthreads();                  // B3: thr ready, hist zeroed

            // ---- collect candidates (recompute d: bitwise same as HSTEP) --
            const float thrf = __uint_as_float(s_thr);
#define CSTEP(i) { const float dx = px##i - cx, dy = py##i - cy, dz = pz##i - cz; \
        const float d = fmaf(dz, dz, fmaf(dy, dy, dx * dx)); \
        if (d < thrf) { const u32 sl = atomicAdd(&cnt, 1u); \
                        if (sl < (u32)CAP) cand[sl] = d; } }
            CSTEP(0)  CSTEP(1)  CSTEP(2)  CSTEP(3)
            CSTEP(4)  CSTEP(5)  CSTEP(6)  CSTEP(7)
            CSTEP(8)  CSTEP(9)  CSTEP(10) CSTEP(11)
            CSTEP(12) CSTEP(13) CSTEP(14) CSTEP(15)
            __syncthreads();                  // B4: candidates ready

            // ---- rank-select 11 smallest (wave 0); then reset cnt ---------
            if (wid == 0) {
                const u32 n = min(cnt, (u32)CAP);
                for (u32 base = 0; base < n; base += 64) {
                    const u32 idx = base + (u32)lane;
                    const float vv = (idx < n) ? cand[idx] : 3.0e38f;
                    u32 r = 0;
                    for (u32 jj = 0; jj < n; ++jj) {
                        const float w = cand[jj];
                        r += (w < vv || (w == vv && jj < idx)) ? 1u : 0u;
                    }
                    if (idx < n && r < (u32)KP1)
                        topd[(b * N_SEEDS + s) * KP1 + r] = sqrtf(vv);
                }
                if (lane == 0) cnt = 0u;      // safe: next collect is after B3
            }
        }
    }
}

// ---------------------------------------------------------------------------
// stats (UNCHANGED): overall_mean over [:,:,1:], per-seed means, unbiased
// variance; fp64 accumulation.
// ---------------------------------------------------------------------------
__global__ __launch_bounds__(256) void stats_kernel(const float* __restrict__ topd,
                                                    float* __restrict__ out, int B) {
    const int pairs = B * N_SEEDS;
    const int total = pairs * KP1;
    const int t = threadIdx.x;
    __shared__ double red[256];
    __shared__ double om_s;

    double s1 = 0.0;
    for (int i = t; i < total; i += 256)
        if (i % KP1 != 0) s1 += (double)topd[i];
    red[t] = s1;
    __syncthreads();
    for (int off = 128; off > 0; off >>= 1) {
        if (t < off) red[t] += red[t + off];
        __syncthreads();
    }
    if (t == 0) om_s = red[0] / (double)(pairs * (KP1 - 1));
    __syncthreads();
    const double om = om_s;

    double sm = 0.0, sm2 = 0.0;
    for (int pr = t; pr < pairs; pr += 256) {
        double acc = 0.0;
        for (int j = 0; j < KP1; ++j) acc += (double)topd[pr * KP1 + j];
        const double m = acc / (om * (double)KP1);
        sm += m;
        sm2 += m * m;
    }
    red[t] = sm;
    __syncthreads();
    for (int off = 128; off > 0; off >>= 1) {
        if (t < off) red[t] += red[t + off];
        __syncthreads();
    }
    double Sm = 0.0;
    if (t == 0) Sm = red[0];
    __syncthreads();
    red[t] = sm2;
    __syncthreads();
    for (int off = 128; off > 0; off >>= 1) {
        if (t < off) red[t] += red[t + off];
        __syncthreads();
    }
    if (t == 0) {
        const double var = (red[0] - Sm * Sm / (double)pairs) / (double)(pairs - 1);
        out[0] = (float)var;
    }
}

// ---------------------------------------------------------------------------
extern "C" void kernel_launch(void* const* d_in, const int* in_sizes, int n_in,
                              void* d_out, int out_size, void* d_ws, size_t ws_size,
                              hipStream_t stream) {
    const float* pcs = (const float*)d_in[0];
    const int B = in_sizes[0] / (N_PTS * 3);

    int*   seeds = (int*)d_ws;
    float* topd  = (float*)((char*)d_ws + 8192);
    float* out   = (float*)d_out;

    // seeds must start at -1 every launch (graph replays don't re-poison)
    hipMemsetAsync(d_ws, 0xFF, 8192, stream);

    fused_kernel<<<B * (1 + NKNN), 1024, 0, stream>>>(pcs, seeds, topd, B);
    stats_kernel<<<1, 256, 0, stream>>>(topd, out, B);
}

// Round 8
// 96.867 us; speedup vs baseline: 1.3975x; 1.1356x over previous
//
#include <hip/hip_runtime.h>

#pragma clang fp contract(off)

#define N_PTS   16384
#define N_SEEDS 20
#define KP1     11      // K+1, K=10
#define NBIN    512     // bits(d2) >> 22 : exponent + 1 mantissa bit
#define NREP    32      // hist[bin*32 + (t&31)] -> bank == t&31 (conflict-free)
#define CAP     4096    // candidate buffer; also LDS pad: >80KB total -> 1 block/CU
#define NKNN    3       // knn-role blocks per batch

typedef unsigned long long u64;
typedef unsigned int       u32;

__device__ __forceinline__ u64 shfl_xor_u64(u64 v, int off) {
    int lo = __shfl_xor((int)(u32)(v & 0xffffffffull), off);
    int hi = __shfl_xor((int)(u32)(v >> 32), off);
    return ((u64)(u32)hi << 32) | (u32)lo;
}

#define FDECL(i) float px##i, py##i, pz##i, dd##i = 1e10f;
#define LOADPTS(P4)                                                         \
    {   const int f4 = t * 12;                                              \
        const float4 q0 = P4[f4+0],  q1 = P4[f4+1],  q2  = P4[f4+2];        \
        const float4 q3 = P4[f4+3],  q4 = P4[f4+4],  q5  = P4[f4+5];        \
        const float4 q6 = P4[f4+6],  q7 = P4[f4+7],  q8  = P4[f4+8];        \
        const float4 q9 = P4[f4+9],  q10 = P4[f4+10], q11 = P4[f4+11];      \
        px0 =q0.x;  py0 =q0.y;  pz0 =q0.z;                                  \
        px1 =q0.w;  py1 =q1.x;  pz1 =q1.y;                                  \
        px2 =q1.z;  py2 =q1.w;  pz2 =q2.x;                                  \
        px3 =q2.y;  py3 =q2.z;  pz3 =q2.w;                                  \
        px4 =q3.x;  py4 =q3.y;  pz4 =q3.z;                                  \
        px5 =q3.w;  py5 =q4.x;  pz5 =q4.y;                                  \
        px6 =q4.z;  py6 =q4.w;  pz6 =q5.x;                                  \
        px7 =q5.y;  py7 =q5.z;  pz7 =q5.w;                                  \
        px8 =q6.x;  py8 =q6.y;  pz8 =q6.z;                                  \
        px9 =q6.w;  py9 =q7.x;  pz9 =q7.y;                                  \
        px10=q7.z;  py10=q7.w;  pz10=q8.x;                                  \
        px11=q8.y;  py11=q8.z;  pz11=q8.w;                                  \
        px12=q9.x;  py12=q9.y;  pz12=q9.z;                                  \
        px13=q9.w;  py13=q10.x; pz13=q10.y;                                 \
        px14=q10.z; py14=q10.w; pz14=q11.x;                                 \
        px15=q11.y; py15=q11.z; pz15=q11.w; }

// ---------------------------------------------------------------------------
// One kernel, three roles, all concurrent (256 blocks x 1024 thr, ~84KB LDS
// -> exactly 1 block/CU on 256 CUs -> guaranteed co-residency for spins):
//   bid <  B : FPS for batch bid (bitwise-frozen round-4 logic); publishes
//              seeds[] with agent-release stores.
//   bid >= B : kNN radix-select; j=(bid-B)/B, b=(bid-B)%B, handles seeds
//              {j, j+3, ...}. After last seed: threadfence + release-add done.
//   bid == B : additionally spins on done==NKNN*B-1 (init -1), fences,
//              computes stats in-kernel.
// ---------------------------------------------------------------------------
__global__ __launch_bounds__(1024) void fused_kernel(const float* __restrict__ pcs,
                                                     int* __restrict__ seeds,
                                                     int* __restrict__ done,
                                                     float* __restrict__ topd,
                                                     float* __restrict__ out,
                                                     int B) {
    __shared__ alignas(16) u32 hist[NBIN * NREP];   // 64 KB (knn) / f64 scratch (stats)
    __shared__ u32   part[NBIN];
    __shared__ float cand[CAP];                     // 16 KB (also the >80KB pad)
    __shared__ u32   cnt;
    __shared__ u32   s_thr;
    __shared__ int   s_sid;
    __shared__ u64   s_key[2][16];                  // fps role
    __shared__ float s_cx[2][16], s_cy[2][16], s_cz[2][16];

    const int bid  = blockIdx.x;
    const int t    = threadIdx.x;
    const int lane = t & 63;
    const int wid  = t >> 6;

    if (bid < B) {
        // ================= FPS role (frozen, proven absmax 0.0) ============
        const float* __restrict__ P  = pcs + (size_t)bid * N_PTS * 3;
        const float4* __restrict__ P4 = (const float4*)P;

        FDECL(0)  FDECL(1)  FDECL(2)  FDECL(3)
        FDECL(4)  FDECL(5)  FDECL(6)  FDECL(7)
        FDECL(8)  FDECL(9)  FDECL(10) FDECL(11)
        FDECL(12) FDECL(13) FDECL(14) FDECL(15)
        LOADPTS(P4)

        float cx = P[0], cy = P[1], cz = P[2];
        int farthest = 0;

        for (int it = 0; it < N_SEEDS; ++it) {
            if (t == 0)
                __hip_atomic_store(&seeds[bid * N_SEEDS + it], farthest,
                                   __ATOMIC_RELEASE, __HIP_MEMORY_SCOPE_AGENT);

            float bestv = -1.0f, bx = 0.f, by = 0.f, bz = 0.f;
            int   besti = 0;
#define FSTEP(i) { const float dx = px##i - cx, dy = py##i - cy, dz = pz##i - cz; \
        const float d  = (dx*dx + dy*dy) + dz*dz; \
        const float nd = fminf(dd##i, d); dd##i = nd; \
        if (nd > bestv) { bestv = nd; besti = t*16 + (i); \
                          bx = px##i; by = py##i; bz = pz##i; } }
            FSTEP(0)  FSTEP(1)  FSTEP(2)  FSTEP(3)
            FSTEP(4)  FSTEP(5)  FSTEP(6)  FSTEP(7)
            FSTEP(8)  FSTEP(9)  FSTEP(10) FSTEP(11)
            FSTEP(12) FSTEP(13) FSTEP(14) FSTEP(15)

            float wmax = bestv;
            for (int off = 32; off; off >>= 1)
                wmax = fmaxf(wmax, __shfl_xor(wmax, off));
            const u64 msk = __ballot(bestv == wmax);
            const int low = __ffsll((unsigned long long)msk) - 1;
            const int wi  = __shfl(besti, low);
            const float wx = __shfl(bx, low);
            const float wy = __shfl(by, low);
            const float wz = __shfl(bz, low);

            const int par = it & 1;
            if (lane == 0) {
                s_key[par][wid] = ((u64)__float_as_uint(wmax) << 32) | (u32)(~(u32)wi);
                s_cx[par][wid] = wx; s_cy[par][wid] = wy; s_cz[par][wid] = wz;
            }
            __syncthreads();

            u64 k = s_key[par][lane & 15];
            for (int off = 8; off; off >>= 1) {
                const u64 o = shfl_xor_u64(k, off);
                if (o > k) k = o;
            }
            const int widx = (int)(~(u32)k);
            farthest = widx;
            const int ww = widx >> 10;
            cx = s_cx[par][ww]; cy = s_cy[par][ww]; cz = s_cz[par][ww];
        }
    } else {
        // ================= kNN-select role =================
        const int kk = bid - B;
        const int b  = kk % B;          // bid ≡ b (mod 8): same XCD as fps block
        const int j  = kk / B;

        const float* __restrict__ P  = pcs + (size_t)b * N_PTS * 3;
        const float4* __restrict__ P4 = (const float4*)P;
        const int rep = t & 31;

        FDECL(0)  FDECL(1)  FDECL(2)  FDECL(3)
        FDECL(4)  FDECL(5)  FDECL(6)  FDECL(7)
        FDECL(8)  FDECL(9)  FDECL(10) FDECL(11)
        FDECL(12) FDECL(13) FDECL(14) FDECL(15)
        LOADPTS(P4)        // dd regs unused -> DCE'd

#pragma unroll
        for (int i = 0; i < (NBIN * NREP) / 1024; ++i) hist[t + i * 1024] = 0u;
        if (t == 0) cnt = 0u;

        for (int s = j; s < N_SEEDS; s += NKNN) {
            if (t == 0) {
                int sv;
                while ((sv = __hip_atomic_load(&seeds[b * N_SEEDS + s],
                               __ATOMIC_ACQUIRE, __HIP_MEMORY_SCOPE_AGENT)) < 0)
                    __builtin_amdgcn_s_sleep(2);
                s_sid = sv;
            }
            __syncthreads();                  // B0: sid ready, hist+cnt zeroed
            const int sid = s_sid;
            const float cx = P[sid*3], cy = P[sid*3+1], cz = P[sid*3+2];

            // distances kept in regs + histogram
            float d0,d1,d2,d3,d4,d5,d6,d7,d8,d9,d10,d11,d12,d13,d14,d15;
#define HSTEP(i) { const float dx = px##i - cx, dy = py##i - cy, dz = pz##i - cz; \
        d##i = fmaf(dz, dz, fmaf(dy, dy, dx * dx)); \
        atomicAdd(&hist[(__float_as_uint(d##i) >> 22) * NREP + rep], 1u); }
            HSTEP(0)  HSTEP(1)  HSTEP(2)  HSTEP(3)
            HSTEP(4)  HSTEP(5)  HSTEP(6)  HSTEP(7)
            HSTEP(8)  HSTEP(9)  HSTEP(10) HSTEP(11)
            HSTEP(12) HSTEP(13) HSTEP(14) HSTEP(15)
            __syncthreads();                  // B1: hist complete

            if (t < NBIN) {
                u32 ssum = 0;
#pragma unroll
                for (int r = 0; r < NREP; ++r)
                    ssum += hist[t * NREP + ((r + t) & (NREP - 1))];
                part[t] = ssum;
            }
            __syncthreads();                  // B2: part[] ready

            if (wid == 0) {
                u32 s8 = 0;
#pragma unroll
                for (int i = 0; i < 8; ++i)
                    s8 += part[lane * 8 + ((i + lane) & 7)];
                u32 cum = s8;
                for (int off = 1; off < 64; off <<= 1) {
                    const u32 o = __shfl_up(cum, off);
                    if (lane >= off) cum += o;
                }
                const u64 mm = __ballot(cum >= (u32)KP1);
                const int L  = __ffsll((unsigned long long)mm) - 1;
                const u32 below = __shfl(cum - s8, L);
                const u32 bc = (lane < 8) ? part[L * 8 + lane] : 0u;
                u32 ic = bc;
                for (int off = 1; off < 8; off <<= 1) {
                    const u32 o = __shfl_up(ic, off);
                    if (lane >= off) ic += o;
                }
                const u64 mm2 = __ballot(lane < 8 && (below + ic) >= (u32)KP1);
                const int l2  = __ffsll((unsigned long long)mm2) - 1;
                if (lane == 0) s_thr = (u32)(L * 8 + l2 + 1) << 22;
            } else {
                if (t == 64) cnt = 0u;        // reset for this seed's collect
                for (int i = t - 64; i < NBIN * NREP; i += 960) hist[i] = 0u;
            }
            __syncthreads();                  // B3: thr ready, hist zeroed, cnt=0

            const float thrf = __uint_as_float(s_thr);
#define CSTEP(i) if (d##i < thrf) { const u32 sl = atomicAdd(&cnt, 1u); \
                                    if (sl < (u32)CAP) cand[sl] = d##i; }
            CSTEP(0)  CSTEP(1)  CSTEP(2)  CSTEP(3)
            CSTEP(4)  CSTEP(5)  CSTEP(6)  CSTEP(7)
            CSTEP(8)  CSTEP(9)  CSTEP(10) CSTEP(11)
            CSTEP(12) CSTEP(13) CSTEP(14) CSTEP(15)
            __syncthreads();                  // B4: candidates ready

            if (wid == 0) {
                const u32 n = min(cnt, (u32)CAP);
                for (u32 base = 0; base < n; base += 64) {
                    const u32 idx = base + (u32)lane;
                    const float vv = (idx < n) ? cand[idx] : 3.0e38f;
                    u32 r = 0;
                    for (u32 jj = 0; jj < n; ++jj) {
                        const float w = cand[jj];
                        r += (w < vv || (w == vv && jj < idx)) ? 1u : 0u;
                    }
                    if (idx < n && r < (u32)KP1)
                        topd[(b * N_SEEDS + s) * KP1 + r] = sqrtf(vv);
                }
            }
        }

        // -------- signal completion (topd visible at agent scope) ----------
        __syncthreads();
        if (t == 0) {
            __threadfence();
            __hip_atomic_fetch_add(done, 1, __ATOMIC_RELEASE,
                                   __HIP_MEMORY_SCOPE_AGENT);
        }

        // ================= stats role (block B only) =======================
        if (bid == B) {
            const int target = NKNN * B - 1;      // done init = -1 (0xFF memset)
            if (t == 0) {
                while (__hip_atomic_load(done, __ATOMIC_ACQUIRE,
                                         __HIP_MEMORY_SCOPE_AGENT) != target)
                    __builtin_amdgcn_s_sleep(8);
            }
            __syncthreads();
            __threadfence();    // order the acquire above before topd reads

            const int pairs = B * N_SEEDS;
            const int total = pairs * KP1;
            double* red = (double*)hist;          // 8 KB scratch, hist is dead

            double s1 = 0.0;
            for (int i = t; i < total; i += 1024)
                if (i % KP1 != 0) s1 += (double)topd[i];
            red[t] = s1;
            __syncthreads();
            for (int off = 512; off; off >>= 1) {
                if (t < off) red[t] += red[t + off];
                __syncthreads();
            }
            const double om = red[0] / (double)(pairs * (KP1 - 1));

            double sm = 0.0, sm2 = 0.0;
            for (int pr = t; pr < pairs; pr += 1024) {
                double acc = 0.0;
                for (int jj = 0; jj < KP1; ++jj) acc += (double)topd[pr * KP1 + jj];
                const double m = acc / (om * (double)KP1);
                sm += m;
                sm2 += m * m;
            }
            __syncthreads();
            red[t] = sm;
            __syncthreads();
            for (int off = 512; off; off >>= 1) {
                if (t < off) red[t] += red[t + off];
                __syncthreads();
            }
            const double Sm = red[0];
            __syncthreads();
            red[t] = sm2;
            __syncthreads();
            for (int off = 512; off; off >>= 1) {
                if (t < off) red[t] += red[t + off];
                __syncthreads();
            }
            if (t == 0) {
                const double var = (red[0] - Sm * Sm / (double)pairs)
                                   / (double)(pairs - 1);
                out[0] = (float)var;
            }
        }
    }
}

// ---------------------------------------------------------------------------
extern "C" void kernel_launch(void* const* d_in, const int* in_sizes, int n_in,
                              void* d_out, int out_size, void* d_ws, size_t ws_size,
                              hipStream_t stream) {
    const float* pcs = (const float*)d_in[0];
    const int B = in_sizes[0] / (N_PTS * 3);

    int*   seeds = (int*)d_ws;                          // B*20 ints
    int*   done  = (int*)((char*)d_ws + 5120);          // 1 int, init -1
    float* topd  = (float*)((char*)d_ws + 8192);        // B*20*11 floats
    float* out   = (float*)d_out;

    // seeds -> -1, done -> -1 every launch (graph replays don't re-poison)
    (void)hipMemsetAsync(d_ws, 0xFF, 8192, stream);

    fused_kernel<<<B * (1 + NKNN), 1024, 0, stream>>>(pcs, seeds, done, topd, out, B);
}

// Round 9
// 67.780 us; speedup vs baseline: 1.9972x; 1.4291x over previous
//
#include <hip/hip_runtime.h>

#pragma clang fp contract(off)

#define N_PTS   16384
#define N_SEEDS 20
#define KP1     11      // K+1, K=10
#define NBIN    512     // bits(d2) >> 22 : exponent + 1 mantissa bit
#define NREP    32      // hist[bin*32 + (t&31)] -> bank == t&31 (conflict-free)
#define CAP     4096    // candidate buffer; also LDS pad: >80KB total -> 1 block/CU
#define NKNN    3       // knn-role blocks per batch

typedef unsigned long long u64;
typedef unsigned int       u32;

__device__ __forceinline__ u64 shfl_xor_u64(u64 v, int off) {
    int lo = __shfl_xor((int)(u32)(v & 0xffffffffull), off);
    int hi = __shfl_xor((int)(u32)(v >> 32), off);
    return ((u64)(u32)hi << 32) | (u32)lo;
}

#define FDECL(i) float px##i, py##i, pz##i, dd##i = 1e10f;
#define LOADPTS(P4)                                                         \
    {   const int f4 = t * 12;                                              \
        const float4 q0 = P4[f4+0],  q1 = P4[f4+1],  q2  = P4[f4+2];        \
        const float4 q3 = P4[f4+3],  q4 = P4[f4+4],  q5  = P4[f4+5];        \
        const float4 q6 = P4[f4+6],  q7 = P4[f4+7],  q8  = P4[f4+8];        \
        const float4 q9 = P4[f4+9],  q10 = P4[f4+10], q11 = P4[f4+11];      \
        px0 =q0.x;  py0 =q0.y;  pz0 =q0.z;                                  \
        px1 =q0.w;  py1 =q1.x;  pz1 =q1.y;                                  \
        px2 =q1.z;  py2 =q1.w;  pz2 =q2.x;                                  \
        px3 =q2.y;  py3 =q2.z;  pz3 =q2.w;                                  \
        px4 =q3.x;  py4 =q3.y;  pz4 =q3.z;                                  \
        px5 =q3.w;  py5 =q4.x;  pz5 =q4.y;                                  \
        px6 =q4.z;  py6 =q4.w;  pz6 =q5.x;                                  \
        px7 =q5.y;  py7 =q5.z;  pz7 =q5.w;                                  \
        px8 =q6.x;  py8 =q6.y;  pz8 =q6.z;                                  \
        px9 =q6.w;  py9 =q7.x;  pz9 =q7.y;                                  \
        px10=q7.z;  py10=q7.w;  pz10=q8.x;                                  \
        px11=q8.y;  py11=q8.z;  pz11=q8.w;                                  \
        px12=q9.x;  py12=q9.y;  pz12=q9.z;                                  \
        px13=q9.w;  py13=q10.x; pz13=q10.y;                                 \
        px14=q10.z; py14=q10.w; pz14=q11.x;                                 \
        px15=q11.y; py15=q11.z; pz15=q11.w; }

// ---------------------------------------------------------------------------
// One kernel, three roles, all concurrent (256 blocks x 1024 thr, ~84KB LDS
// -> exactly 1 block/CU on 256 CUs -> guaranteed co-residency for spins):
//   bid <  B : FPS for batch bid (bitwise-frozen round-4 logic); publishes
//              seeds[] with RELAXED agent stores (value IS the payload; no
//              fence/wbL2 on the critical path).
//   bid >= B : kNN radix-select; j=(bid-B)/B, b=(bid-B)%B, handles seeds
//              {j, j+3, ...}, polling seeds with RELAXED agent loads.
//              After last seed: __threadfence() + relaxed add on done.
//   bid == B : additionally polls done==NKNN*B-1 (relaxed; init -1), then
//              __threadfence() and computes stats in-kernel.
// ---------------------------------------------------------------------------
__global__ __launch_bounds__(1024) void fused_kernel(const float* __restrict__ pcs,
                                                     int* __restrict__ seeds,
                                                     int* __restrict__ done,
                                                     float* __restrict__ topd,
                                                     float* __restrict__ out,
                                                     int B) {
    __shared__ alignas(16) u32 hist[NBIN * NREP];   // 64 KB (knn) / f64 scratch (stats)
    __shared__ u32   part[NBIN];
    __shared__ float cand[CAP];                     // 16 KB (also the >80KB pad)
    __shared__ u32   cnt;
    __shared__ u32   s_thr;
    __shared__ int   s_sid;
    __shared__ u64   s_key[2][16];                  // fps role
    __shared__ float s_cx[2][16], s_cy[2][16], s_cz[2][16];

    const int bid  = blockIdx.x;
    const int t    = threadIdx.x;
    const int lane = t & 63;
    const int wid  = t >> 6;

    if (bid < B) {
        // ================= FPS role (frozen, proven absmax 0.0) ============
        const float* __restrict__ P  = pcs + (size_t)bid * N_PTS * 3;
        const float4* __restrict__ P4 = (const float4*)P;

        FDECL(0)  FDECL(1)  FDECL(2)  FDECL(3)
        FDECL(4)  FDECL(5)  FDECL(6)  FDECL(7)
        FDECL(8)  FDECL(9)  FDECL(10) FDECL(11)
        FDECL(12) FDECL(13) FDECL(14) FDECL(15)
        LOADPTS(P4)

        float cx = P[0], cy = P[1], cz = P[2];
        int farthest = 0;

        for (int it = 0; it < N_SEEDS; ++it) {
            if (t == 0)    // RELAXED: value-only payload, no fence machinery
                __hip_atomic_store(&seeds[bid * N_SEEDS + it], farthest,
                                   __ATOMIC_RELAXED, __HIP_MEMORY_SCOPE_AGENT);

            float bestv = -1.0f, bx = 0.f, by = 0.f, bz = 0.f;
            int   besti = 0;
#define FSTEP(i) { const float dx = px##i - cx, dy = py##i - cy, dz = pz##i - cz; \
        const float d  = (dx*dx + dy*dy) + dz*dz; \
        const float nd = fminf(dd##i, d); dd##i = nd; \
        if (nd > bestv) { bestv = nd; besti = t*16 + (i); \
                          bx = px##i; by = py##i; bz = pz##i; } }
            FSTEP(0)  FSTEP(1)  FSTEP(2)  FSTEP(3)
            FSTEP(4)  FSTEP(5)  FSTEP(6)  FSTEP(7)
            FSTEP(8)  FSTEP(9)  FSTEP(10) FSTEP(11)
            FSTEP(12) FSTEP(13) FSTEP(14) FSTEP(15)

            float wmax = bestv;
            for (int off = 32; off; off >>= 1)
                wmax = fmaxf(wmax, __shfl_xor(wmax, off));
            const u64 msk = __ballot(bestv == wmax);
            const int low = __ffsll((unsigned long long)msk) - 1;
            const int wi  = __shfl(besti, low);
            const float wx = __shfl(bx, low);
            const float wy = __shfl(by, low);
            const float wz = __shfl(bz, low);

            const int par = it & 1;
            if (lane == 0) {
                s_key[par][wid] = ((u64)__float_as_uint(wmax) << 32) | (u32)(~(u32)wi);
                s_cx[par][wid] = wx; s_cy[par][wid] = wy; s_cz[par][wid] = wz;
            }
            __syncthreads();

            u64 k = s_key[par][lane & 15];
            for (int off = 8; off; off >>= 1) {
                const u64 o = shfl_xor_u64(k, off);
                if (o > k) k = o;
            }
            const int widx = (int)(~(u32)k);
            farthest = widx;
            const int ww = widx >> 10;
            cx = s_cx[par][ww]; cy = s_cy[par][ww]; cz = s_cz[par][ww];
        }
    } else {
        // ================= kNN-select role =================
        const int kk = bid - B;
        const int b  = kk % B;          // bid ≡ b (mod 8): same XCD as fps block
        const int j  = kk / B;

        const float* __restrict__ P  = pcs + (size_t)b * N_PTS * 3;
        const float4* __restrict__ P4 = (const float4*)P;
        const int rep = t & 31;

        FDECL(0)  FDECL(1)  FDECL(2)  FDECL(3)
        FDECL(4)  FDECL(5)  FDECL(6)  FDECL(7)
        FDECL(8)  FDECL(9)  FDECL(10) FDECL(11)
        FDECL(12) FDECL(13) FDECL(14) FDECL(15)
        LOADPTS(P4)        // dd regs unused -> DCE'd

#pragma unroll
        for (int i = 0; i < (NBIN * NREP) / 1024; ++i) hist[t + i * 1024] = 0u;
        if (t == 0) cnt = 0u;

        for (int s = j; s < N_SEEDS; s += NKNN) {
            if (t == 0) {   // RELAXED poll: seed index is the whole payload
                int sv;
                while ((sv = __hip_atomic_load(&seeds[b * N_SEEDS + s],
                               __ATOMIC_RELAXED, __HIP_MEMORY_SCOPE_AGENT)) < 0)
                    __builtin_amdgcn_s_sleep(2);
                s_sid = sv;
            }
            __syncthreads();                  // B0: sid ready, hist+cnt zeroed
            const int sid = s_sid;
            const float cx = P[sid*3], cy = P[sid*3+1], cz = P[sid*3+2];

            // distances kept in regs + histogram
            float d0,d1,d2,d3,d4,d5,d6,d7,d8,d9,d10,d11,d12,d13,d14,d15;
#define HSTEP(i) { const float dx = px##i - cx, dy = py##i - cy, dz = pz##i - cz; \
        d##i = fmaf(dz, dz, fmaf(dy, dy, dx * dx)); \
        atomicAdd(&hist[(__float_as_uint(d##i) >> 22) * NREP + rep], 1u); }
            HSTEP(0)  HSTEP(1)  HSTEP(2)  HSTEP(3)
            HSTEP(4)  HSTEP(5)  HSTEP(6)  HSTEP(7)
            HSTEP(8)  HSTEP(9)  HSTEP(10) HSTEP(11)
            HSTEP(12) HSTEP(13) HSTEP(14) HSTEP(15)
            __syncthreads();                  // B1: hist complete

            if (t < NBIN) {
                u32 ssum = 0;
#pragma unroll
                for (int r = 0; r < NREP; ++r)
                    ssum += hist[t * NREP + ((r + t) & (NREP - 1))];
                part[t] = ssum;
            }
            __syncthreads();                  // B2: part[] ready

            if (wid == 0) {
                u32 s8 = 0;
#pragma unroll
                for (int i = 0; i < 8; ++i)
                    s8 += part[lane * 8 + ((i + lane) & 7)];
                u32 cum = s8;
                for (int off = 1; off < 64; off <<= 1) {
                    const u32 o = __shfl_up(cum, off);
                    if (lane >= off) cum += o;
                }
                const u64 mm = __ballot(cum >= (u32)KP1);
                const int L  = __ffsll((unsigned long long)mm) - 1;
                const u32 below = __shfl(cum - s8, L);
                const u32 bc = (lane < 8) ? part[L * 8 + lane] : 0u;
                u32 ic = bc;
                for (int off = 1; off < 8; off <<= 1) {
                    const u32 o = __shfl_up(ic, off);
                    if (lane >= off) ic += o;
                }
                const u64 mm2 = __ballot(lane < 8 && (below + ic) >= (u32)KP1);
                const int l2  = __ffsll((unsigned long long)mm2) - 1;
                if (lane == 0) s_thr = (u32)(L * 8 + l2 + 1) << 22;
            } else {
                if (t == 64) cnt = 0u;        // reset for this seed's collect
                for (int i = t - 64; i < NBIN * NREP; i += 960) hist[i] = 0u;
            }
            __syncthreads();                  // B3: thr ready, hist zeroed, cnt=0

            const float thrf = __uint_as_float(s_thr);
#define CSTEP(i) if (d##i < thrf) { const u32 sl = atomicAdd(&cnt, 1u); \
                                    if (sl < (u32)CAP) cand[sl] = d##i; }
            CSTEP(0)  CSTEP(1)  CSTEP(2)  CSTEP(3)
            CSTEP(4)  CSTEP(5)  CSTEP(6)  CSTEP(7)
            CSTEP(8)  CSTEP(9)  CSTEP(10) CSTEP(11)
            CSTEP(12) CSTEP(13) CSTEP(14) CSTEP(15)
            __syncthreads();                  // B4: candidates ready

            if (wid == 0) {
                const u32 n = min(cnt, (u32)CAP);
                for (u32 base = 0; base < n; base += 64) {
                    const u32 idx = base + (u32)lane;
                    const float vv = (idx < n) ? cand[idx] : 3.0e38f;
                    u32 r = 0;
                    for (u32 jj = 0; jj < n; ++jj) {
                        const float w = cand[jj];
                        r += (w < vv || (w == vv && jj < idx)) ? 1u : 0u;
                    }
                    if (idx < n && r < (u32)KP1)
                        topd[(b * N_SEEDS + s) * KP1 + r] = sqrtf(vv);
                }
            }
        }

        // -------- signal completion (one fence per block, off hot path) ----
        __syncthreads();
        if (t == 0) {
            __threadfence();                  // make topd visible at agent scope
            __hip_atomic_fetch_add(done, 1, __ATOMIC_RELAXED,
                                   __HIP_MEMORY_SCOPE_AGENT);
        }

        // ================= stats role (block B only) =======================
        if (bid == B) {
            const int target = NKNN * B - 1;      // done init = -1 (0xFF memset)
            if (t == 0) {
                while (__hip_atomic_load(done, __ATOMIC_RELAXED,
                                         __HIP_MEMORY_SCOPE_AGENT) != target)
                    __builtin_amdgcn_s_sleep(8);
            }
            __syncthreads();
            __threadfence();    // acquire side: invalidate before topd reads

            const int pairs = B * N_SEEDS;
            const int total = pairs * KP1;
            double* red = (double*)hist;          // 8 KB scratch, hist is dead

            double s1 = 0.0;
            for (int i = t; i < total; i += 1024)
                if (i % KP1 != 0) s1 += (double)topd[i];
            red[t] = s1;
            __syncthreads();
            for (int off = 512; off; off >>= 1) {
                if (t < off) red[t] += red[t + off];
                __syncthreads();
            }
            const double om = red[0] / (double)(pairs * (KP1 - 1));

            double sm = 0.0, sm2 = 0.0;
            for (int pr = t; pr < pairs; pr += 1024) {
                double acc = 0.0;
                for (int jj = 0; jj < KP1; ++jj) acc += (double)topd[pr * KP1 + jj];
                const double m = acc / (om * (double)KP1);
                sm += m;
                sm2 += m * m;
            }
            __syncthreads();
            red[t] = sm;
            __syncthreads();
            for (int off = 512; off; off >>= 1) {
                if (t < off) red[t] += red[t + off];
                __syncthreads();
            }
            const double Sm = red[0];
            __syncthreads();
            red[t] = sm2;
            __syncthreads();
            for (int off = 512; off; off >>= 1) {
                if (t < off) red[t] += red[t + off];
                __syncthreads();
            }
            if (t == 0) {
                const double var = (red[0] - Sm * Sm / (double)pairs)
                                   / (double)(pairs - 1);
                out[0] = (float)var;
            }
        }
    }
}

// ---------------------------------------------------------------------------
extern "C" void kernel_launch(void* const* d_in, const int* in_sizes, int n_in,
                              void* d_out, int out_size, void* d_ws, size_t ws_size,
                              hipStream_t stream) {
    const float* pcs = (const float*)d_in[0];
    const int B = in_sizes[0] / (N_PTS * 3);

    int*   seeds = (int*)d_ws;                          // B*20 ints
    int*   done  = (int*)((char*)d_ws + 5120);          // 1 int, init -1
    float* topd  = (float*)((char*)d_ws + 8192);        // B*20*11 floats
    float* out   = (float*)d_out;

    // seeds -> -1, done -> -1 every launch (graph replays don't re-poison)
    (void)hipMemsetAsync(d_ws, 0xFF, 8192, stream);

    fused_kernel<<<B * (1 + NKNN), 1024, 0, stream>>>(pcs, seeds, done, topd, out, B);
}